// Round 1
// baseline (2979.982 us; speedup 1.0000x reference)
//
#include <hip/hip_runtime.h>

// SimpleRNN (relu) scan: B=512, T=512, D=64, H=512, O=1.
// Design: 32 workgroups x 16 batch rows; per-wg serial scan over T with
// h kept in LDS (A-fragment order, bf16). Augmented GEMM per step:
//   h_t = relu([x_t | h_{t-1}] @ [W_x; W_h] + b),  K = 576, via
// mfma_f32_16x16x32_bf16. Weights streamed from L2 in B-fragment order
// (prep kernel lays them out so each wave load is a contiguous 1KB dwordx4).

#define T_STEPS 512
#define D_IN    64
#define H_DIM   512
#define KC_N    18          // (64+512)/32 K-chunks
#define ROWS    16          // batch rows per workgroup
#define NWG     32          // 512/16
#define THREADS 512         // 8 waves; wave w owns columns [w*64, w*64+64)

typedef float  floatx4 __attribute__((ext_vector_type(4)));
typedef __bf16 bf16x8  __attribute__((ext_vector_type(8)));

__device__ __forceinline__ unsigned short f2b(float f) {
    union { float f; unsigned int u; } v; v.f = f;
    unsigned int u = v.u;
    return (unsigned short)((u + 0x7FFFu + ((u >> 16) & 1u)) >> 16);  // RNE
}

// WT element f = ((ng*18 + kc)*64 + lane)*8 + j  encodes B[k][n]:
//   n = ng*16 + (lane&15),  k = kc*32 + (lane>>4)*8 + j
//   B[k][n] = k<64 ? W_x[k][n] : W_h[k-64][n]   (bf16)
__global__ void prep_kernel(const float* __restrict__ Wx, const float* __restrict__ Wh,
                            unsigned short* __restrict__ WT) {
    int f = blockIdx.x * 256 + threadIdx.x;
    if (f >= 512 * 576) return;
    int j    = f & 7;
    int lane = (f >> 3) & 63;
    int blk  = f >> 9;           // ng*18 + kc
    int kc   = blk % 18;
    int ng   = blk / 18;
    int n = ng * 16 + (lane & 15);
    int k = kc * 32 + (lane >> 4) * 8 + j;
    float val = (k < 64) ? Wx[k * 512 + n] : Wh[(k - 64) * 512 + n];
    WT[f] = f2b(val);
}

__global__ __launch_bounds__(THREADS)
void rnn_scan_kernel(const float* __restrict__ x, const unsigned short* __restrict__ WT,
                     const float* __restrict__ b_rnn, const float* __restrict__ Wd,
                     const float* __restrict__ bd, float* __restrict__ out) {
    // A-fragment store: afrag[(kc*64 + lane)*8 + j] = [x_t | h]{m = lane&15,
    // k = kc*32 + (lane>>4)*8 + j}. kc 0..1 = x (k<64), kc 2..17 = h (k=64+col).
    __shared__ __attribute__((aligned(16))) unsigned short afrag[KC_N * 64 * 8]; // 18 KB
    __shared__ float red[16 * 8];

    const int tid  = threadIdx.x;
    const int lane = tid & 63;
    const int w    = tid >> 6;       // wave 0..7
    const int c    = lane & 15;
    const int quad = lane >> 4;
    const int r0   = blockIdx.x * ROWS;

    // per-lane column constants (C-frag col = w*64 + nt*16 + c)
    float bias[4], wd[4];
#pragma unroll
    for (int nt = 0; nt < 4; ++nt) {
        int col = w * 64 + nt * 16 + c;
        bias[nt] = b_rnn[col];
        wd[nt]   = Wd[col];
    }

    // zero h region of afrag (elements [1024, 9216))
    for (int i = tid; i < 8192; i += THREADS) afrag[1024 + i] = 0;

    // x staging: thread handles elements e = 2*tid, 2*tid+1 of the 16x64 x-tile
    const int xe = tid * 2;
    const int xm = xe >> 6;          // row 0..15
    const int xk = xe & 63;          // k 0..63 (even)
    const int xidx = ((xk >> 5) * 64 + ((xk >> 3) & 3) * 16 + xm) * 8 + (xk & 7);
    const float* xbase = x + ((size_t)(r0 + xm) * T_STEPS) * D_IN + xk;

    {   // load x_0
        float f0 = xbase[0], f1 = xbase[1];
        unsigned int pk = (unsigned int)f2b(f0) | ((unsigned int)f2b(f1) << 16);
        *reinterpret_cast<unsigned int*>(&afrag[xidx]) = pk;
    }
    __syncthreads();

    const unsigned short* bbase[4];
#pragma unroll
    for (int nt = 0; nt < 4; ++nt)
        bbase[nt] = WT + ((size_t)((w * 4 + nt) * 18) * 64 + lane) * 8;

    float hv[4][4];

    for (int t = 0; t < T_STEPS; ++t) {
        // prefetch x_{t+1} into registers early (hide HBM latency under MFMA)
        float xf0 = 0.f, xf1 = 0.f;
        if (t < T_STEPS - 1) {
            const float* xp = xbase + (size_t)(t + 1) * D_IN;
            xf0 = xp[0]; xf1 = xp[1];
        }

        floatx4 acc[4];
#pragma unroll
        for (int nt = 0; nt < 4; ++nt) acc[nt] = (floatx4){0.f, 0.f, 0.f, 0.f};

        // K loop with 2-deep register prefetch ring (A from LDS, B from L2)
        bf16x8 aReg[3];
        bf16x8 bReg[3][4];
#pragma unroll
        for (int p = 0; p < 2; ++p) {
            aReg[p] = *reinterpret_cast<const bf16x8*>(&afrag[(p * 64 + lane) * 8]);
#pragma unroll
            for (int nt = 0; nt < 4; ++nt)
                bReg[p][nt] = *reinterpret_cast<const bf16x8*>(bbase[nt] + p * 512);
        }
#pragma unroll
        for (int kc = 0; kc < KC_N; ++kc) {
            const int cur = kc % 3;
            const int pf  = kc + 2;
            if (pf < KC_N) {
                const int s = pf % 3;
                aReg[s] = *reinterpret_cast<const bf16x8*>(&afrag[(pf * 64 + lane) * 8]);
#pragma unroll
                for (int nt = 0; nt < 4; ++nt)
                    bReg[s][nt] = *reinterpret_cast<const bf16x8*>(bbase[nt] + pf * 512);
            }
#pragma unroll
            for (int nt = 0; nt < 4; ++nt)
                acc[nt] = __builtin_amdgcn_mfma_f32_16x16x32_bf16(aReg[cur], bReg[cur][nt], acc[nt], 0, 0, 0);
        }

        __syncthreads();   // all waves done reading afrag for this step

        if (t < T_STEPS - 1) {
            // write h_t = relu(acc + b) back in A-frag order (k = 64 + col)
#pragma unroll
            for (int nt = 0; nt < 4; ++nt) {
                const int col = w * 64 + nt * 16 + c;
                const int kcd = 2 + (col >> 5);
                const int q2  = (col >> 3) & 3;
                const int j   = col & 7;
#pragma unroll
                for (int r = 0; r < 4; ++r) {
                    const int m = quad * 4 + r;     // C-frag row
                    float v = acc[nt][r] + bias[nt];
                    v = v > 0.f ? v : 0.f;
                    afrag[(kcd * 64 + q2 * 16 + m) * 8 + j] = f2b(v);
                }
            }
            // write prefetched x_{t+1}
            unsigned int pk = (unsigned int)f2b(xf0) | ((unsigned int)f2b(xf1) << 16);
            *reinterpret_cast<unsigned int*>(&afrag[xidx]) = pk;
        } else {
            // keep fp32 h_last for the output head
#pragma unroll
            for (int nt = 0; nt < 4; ++nt)
#pragma unroll
                for (int r = 0; r < 4; ++r) {
                    float v = acc[nt][r] + bias[nt];
                    hv[nt][r] = v > 0.f ? v : 0.f;
                }
        }
        __syncthreads();
    }

    // out[b] = relu(h_last[b,:] . Wd + bd)
    float part[4];
#pragma unroll
    for (int r = 0; r < 4; ++r) {
        part[r] = 0.f;
#pragma unroll
        for (int nt = 0; nt < 4; ++nt) part[r] += hv[nt][r] * wd[nt];
    }
#pragma unroll
    for (int off = 1; off < 16; off <<= 1) {
#pragma unroll
        for (int r = 0; r < 4; ++r) part[r] += __shfl_xor(part[r], off, 64);
    }
    if (c == 0) {
#pragma unroll
        for (int r = 0; r < 4; ++r) red[(quad * 4 + r) * 8 + w] = part[r];
    }
    __syncthreads();
    if (tid < 16) {
        float s = 0.f;
#pragma unroll
        for (int i = 0; i < 8; ++i) s += red[tid * 8 + i];
        s += bd[0];
        out[r0 + tid] = s > 0.f ? s : 0.f;
    }
}

extern "C" void kernel_launch(void* const* d_in, const int* in_sizes, int n_in,
                              void* d_out, int out_size, void* d_ws, size_t ws_size,
                              hipStream_t stream) {
    const float* x    = (const float*)d_in[0];
    const float* Wx   = (const float*)d_in[1];
    const float* Wh   = (const float*)d_in[2];
    const float* brnn = (const float*)d_in[3];
    const float* Wd   = (const float*)d_in[4];
    const float* bd   = (const float*)d_in[5];
    float* out = (float*)d_out;
    unsigned short* WT = (unsigned short*)d_ws;   // 512*576*2 = 589824 B

    prep_kernel<<<(512 * 576 + 255) / 256, 256, 0, stream>>>(Wx, Wh, WT);
    rnn_scan_kernel<<<NWG, THREADS, 0, stream>>>(x, WT, brnn, Wd, bd, out);
}

// Round 2
// 1568.245 us; speedup vs baseline: 1.9002x; 1.9002x over previous
//
#include <hip/hip_runtime.h>

// SimpleRNN (relu) scan: B=512, T=512, D=64, H=512, O=1.
// R2 design: register-resident weights, 2-way N-split per batch-group.
//  - 32 groups x 16 batch rows; each group = 2 WGs (s=0: cols 0..255, s=1: 256..511).
//  - Each WG holds its W slice (576x256 bf16) in 144 VGPRs/lane; no weight streaming.
//  - Per step: compute own 256 cols of h_t, write slice to global (A-frag order,
//    double-buffered), release flag; peer polls + global_load_lds DMAs 8KB into LDS.
//  - K-loop ordered x+own-first so poll/DMA hides under compute.

#define T_STEPS 512
#define D_IN    64
#define ROWS    16
#define THREADS 512

#define WT_OFF    0
#define WT_BYTES  (512*576*2)            // 589824
#define HBUF_OFF  WT_BYTES
#define HBUF_BYTES (32*2*2*8192)         // 1 MiB
#define FLAGS_OFF (HBUF_OFF + HBUF_BYTES)
#define FLAGS_BYTES (32*2*512*4)         // 128 KiB

typedef float  floatx4 __attribute__((ext_vector_type(4)));
typedef __bf16 bf16x8  __attribute__((ext_vector_type(8)));

__device__ __forceinline__ unsigned short f2b(float f) {
    union { float f; unsigned int u; } v; v.f = f;
    unsigned int u = v.u;
    return (unsigned short)((u + 0x7FFFu + ((u >> 16) & 1u)) >> 16);  // RNE
}

// WT element f = ((ng*18 + kc)*64 + lane)*8 + j  encodes B[k][n]:
//   n = ng*16 + (lane&15),  k = kc*32 + (lane>>4)*8 + j
__global__ void prep_kernel(const float* __restrict__ Wx, const float* __restrict__ Wh,
                            unsigned short* __restrict__ WT) {
    int f = blockIdx.x * 256 + threadIdx.x;
    if (f >= 512 * 576) return;
    int j    = f & 7;
    int lane = (f >> 3) & 63;
    int blk  = f >> 9;
    int kc   = blk % 18;
    int ng   = blk / 18;
    int n = ng * 16 + (lane & 15);
    int k = kc * 32 + (lane >> 4) * 8 + j;
    float val = (k < 64) ? Wx[k * 512 + n] : Wh[(k - 64) * 512 + n];
    WT[f] = f2b(val);
}

__global__ __launch_bounds__(THREADS)
void rnn_scan_kernel(const float* __restrict__ x, const unsigned short* __restrict__ WT,
                     const float* __restrict__ b_rnn, const float* __restrict__ Wd,
                     const float* __restrict__ bd, float* __restrict__ out,
                     unsigned short* __restrict__ hbuf, int* __restrict__ flags) {
    // afrag[(kc*64 + lane)*8 + j]: A[m = lane&15, k = kc*32 + (lane>>4)*8 + j]
    // kc 0..1 = x_t (k<64); kc 2..9 = h cols 0..255; kc 10..17 = h cols 256..511.
    __shared__ __attribute__((aligned(16))) unsigned short afrag[18 * 512]; // 18 KB

    const int tid  = threadIdx.x;
    const int lane = tid & 63;
    const int w    = tid >> 6;
    const int c    = lane & 15;
    const int quad = lane >> 4;
    // pair blocks {b, b+32}: likely same XCD under round-robin dispatch
    const int g     = blockIdx.x & 31;
    const int s     = blockIdx.x >> 5;
    const int speer = 1 - s;
    const int r0    = g * ROWS;

    // ---- weights -> registers (slot order: 0..1 = x-part, 2..9 = own, 10..17 = peer K) ----
    bf16x8 wreg[18][2];
#pragma unroll
    for (int i = 0; i < 18; ++i) {
        const int kcp = (i < 2) ? i : (i < 10 ? (2 + s * 8 + (i - 2))
                                              : (2 + speer * 8 + (i - 10)));
#pragma unroll
        for (int nt = 0; nt < 2; ++nt) {
            const int ng = s * 16 + w * 2 + nt;
            wreg[i][nt] = *reinterpret_cast<const bf16x8*>(
                WT + (((size_t)ng * 18 + kcp) * 64 + lane) * 8);
        }
    }

    float bias[2];
#pragma unroll
    for (int nt = 0; nt < 2; ++nt)
        bias[nt] = b_rnn[s * 256 + w * 32 + nt * 16 + c];

    // zero h region, stage x_0
    for (int i = tid; i < 8192; i += THREADS) afrag[1024 + i] = 0;
    const int xe = tid * 2;
    const int xm = xe >> 6;
    const int xk = xe & 63;
    const int xidx = ((xk >> 5) * 64 + ((xk >> 3) & 3) * 16 + xm) * 8 + (xk & 7);
    const float* xbase = x + ((size_t)(r0 + xm) * T_STEPS) * D_IN + xk;
    {
        float f0 = xbase[0], f1 = xbase[1];
        *reinterpret_cast<unsigned int*>(&afrag[xidx]) =
            (unsigned int)f2b(f0) | ((unsigned int)f2b(f1) << 16);
    }
    __syncthreads();

    const char* ab = (const char*)afrag;
    const unsigned laneoff = (unsigned)lane * 16u;
    const unsigned ownB  = laneoff + (unsigned)s * 8192u;      // + i*1024, i in [2,10)
    const unsigned peerB = laneoff + (unsigned)speer * 8192u;  // + (i-8)*1024, i in [10,18)
    const int peerLdsByte = (2 + speer * 8) * 1024;
    const int ownLds = (2 + s * 8) * 512;   // short index base

    // epilogue short-offsets within slice (r=0); m = quad*4+r -> +8 per r
    int soff[2];
#pragma unroll
    for (int nt = 0; nt < 2; ++nt) {
        const int cl = w * 32 + nt * 16 + c;
        soff[nt] = (((cl >> 5) * 64) + (((cl >> 3) & 3) * 16) + quad * 4) * 8 + (cl & 7);
    }

    for (int t = 0; t < T_STEPS; ++t) {
        float xf0 = 0.f, xf1 = 0.f;
        if (t < T_STEPS - 1) {
            const float* xp = xbase + (size_t)(t + 1) * D_IN;
            xf0 = xp[0]; xf1 = xp[1];
        }

        floatx4 acc0 = {0.f, 0.f, 0.f, 0.f}, acc1 = {0.f, 0.f, 0.f, 0.f};

        // phase 1: x + own columns (no peer data needed)
#pragma unroll
        for (int i = 0; i < 2; ++i) {
            bf16x8 a = *reinterpret_cast<const bf16x8*>(ab + laneoff + i * 1024);
            acc0 = __builtin_amdgcn_mfma_f32_16x16x32_bf16(a, wreg[i][0], acc0, 0, 0, 0);
            acc1 = __builtin_amdgcn_mfma_f32_16x16x32_bf16(a, wreg[i][1], acc1, 0, 0, 0);
        }
#pragma unroll
        for (int i = 2; i < 10; ++i) {
            bf16x8 a = *reinterpret_cast<const bf16x8*>(ab + ownB + i * 1024);
            acc0 = __builtin_amdgcn_mfma_f32_16x16x32_bf16(a, wreg[i][0], acc0, 0, 0, 0);
            acc1 = __builtin_amdgcn_mfma_f32_16x16x32_bf16(a, wreg[i][1], acc1, 0, 0, 0);
        }

        // wave 0: wait for peer h_{t-1}, DMA 8KB into LDS peer region
        if (w == 0 && t > 0) {
            const int* fp = flags + (g * 2 + speer) * 512 + (t - 1);
            if (lane == 0) {
                int gd = 0;
                while (__hip_atomic_load(fp, __ATOMIC_RELAXED, __HIP_MEMORY_SCOPE_AGENT) == 0
                       && ++gd < (1 << 25)) {}
            }
            __builtin_amdgcn_fence(__ATOMIC_ACQUIRE, "agent");
            const char* gp = (const char*)(hbuf + ((size_t)g * 4 + ((t - 1) & 1) * 2 + speer) * 4096)
                             + laneoff;
#pragma unroll
            for (int q = 0; q < 8; ++q)
                __builtin_amdgcn_global_load_lds(
                    (const __attribute__((address_space(1))) unsigned int*)(gp + q * 1024),
                    (__attribute__((address_space(3))) unsigned int*)((char*)afrag + peerLdsByte + q * 1024),
                    16, 0, 0);
            asm volatile("s_waitcnt vmcnt(0)" ::: "memory");
        }
        __syncthreads();

        // phase 2: peer columns
#pragma unroll
        for (int i = 10; i < 18; ++i) {
            bf16x8 a = *reinterpret_cast<const bf16x8*>(ab + peerB + (i - 8) * 1024);
            acc0 = __builtin_amdgcn_mfma_f32_16x16x32_bf16(a, wreg[i][0], acc0, 0, 0, 0);
            acc1 = __builtin_amdgcn_mfma_f32_16x16x32_bf16(a, wreg[i][1], acc1, 0, 0, 0);
        }

        // epilogue: relu+pack h_t -> own LDS region + global slice (A-frag order)
        unsigned short* hs = hbuf + ((size_t)g * 4 + (t & 1) * 2 + s) * 4096;
#pragma unroll
        for (int nt = 0; nt < 2; ++nt) {
#pragma unroll
            for (int r = 0; r < 4; ++r) {
                float v = (nt ? acc1[r] : acc0[r]) + bias[nt];
                v = v > 0.f ? v : 0.f;
                const unsigned short hb = f2b(v);
                const int so = soff[nt] + r * 8;
                afrag[ownLds + so] = hb;
                hs[so] = hb;
            }
        }
        if (t < T_STEPS - 1)
            *reinterpret_cast<unsigned int*>(&afrag[xidx]) =
                (unsigned int)f2b(xf0) | ((unsigned int)f2b(xf1) << 16);
        __syncthreads();
        if (tid == 0)
            __hip_atomic_store(flags + (g * 2 + s) * 512 + t, 1,
                               __ATOMIC_RELEASE, __HIP_MEMORY_SCOPE_AGENT);
    }

    // ---- output head: only s==0 finalizes (needs peer h_511 slice) ----
    if (s == 0) {
        if (w == 0) {
            const int* fp = flags + (g * 2 + 1) * 512 + 511;
            if (lane == 0) {
                int gd = 0;
                while (__hip_atomic_load(fp, __ATOMIC_RELAXED, __HIP_MEMORY_SCOPE_AGENT) == 0
                       && ++gd < (1 << 25)) {}
            }
            __builtin_amdgcn_fence(__ATOMIC_ACQUIRE, "agent");
            const char* gp = (const char*)(hbuf + ((size_t)g * 4 + 1 * 2 + 1) * 4096) + laneoff;
#pragma unroll
            for (int q = 0; q < 8; ++q)
                __builtin_amdgcn_global_load_lds(
                    (const __attribute__((address_space(1))) unsigned int*)(gp + q * 1024),
                    (__attribute__((address_space(3))) unsigned int*)((char*)afrag + 10240 + q * 1024),
                    16, 0, 0);
            asm volatile("s_waitcnt vmcnt(0)" ::: "memory");
        }
        __syncthreads();

        const int lane5 = lane & 31;
        const int row = w * 2 + (lane >> 5);
        float sum = 0.f;
#pragma unroll
        for (int b2 = 0; b2 < 2; ++b2) {
            const int col0 = lane5 * 16 + b2 * 8;
            const int kcp = 2 + (col0 >> 5);
            const int q2 = (col0 >> 3) & 3;
            const bf16x8 hvv = *reinterpret_cast<const bf16x8*>(&afrag[kcp * 512 + (q2 * 16 + row) * 8]);
#pragma unroll
            for (int jj = 0; jj < 8; ++jj)
                sum += (float)hvv[jj] * Wd[col0 + jj];
        }
#pragma unroll
        for (int off = 1; off < 32; off <<= 1) sum += __shfl_xor(sum, off, 64);
        if (lane5 == 0) {
            float v = sum + bd[0];
            out[r0 + row] = v > 0.f ? v : 0.f;
        }
    }
}

extern "C" void kernel_launch(void* const* d_in, const int* in_sizes, int n_in,
                              void* d_out, int out_size, void* d_ws, size_t ws_size,
                              hipStream_t stream) {
    const float* x    = (const float*)d_in[0];
    const float* Wx   = (const float*)d_in[1];
    const float* Wh   = (const float*)d_in[2];
    const float* brnn = (const float*)d_in[3];
    const float* Wd   = (const float*)d_in[4];
    const float* bd   = (const float*)d_in[5];
    float* out = (float*)d_out;

    char* wsb = (char*)d_ws;
    unsigned short* WT   = (unsigned short*)(wsb + WT_OFF);
    unsigned short* hbuf = (unsigned short*)(wsb + HBUF_OFF);
    int*            flg  = (int*)(wsb + FLAGS_OFF);

    hipMemsetAsync(wsb + FLAGS_OFF, 0, FLAGS_BYTES, stream);
    prep_kernel<<<(512 * 576 + 255) / 256, 256, 0, stream>>>(Wx, Wh, WT);
    rnn_scan_kernel<<<64, THREADS, 0, stream>>>(x, WT, brnn, Wd, bd, out, hbuf, flg);
}